// Round 6
// baseline (624.706 us; speedup 1.0000x reference)
//
#include <hip/hip_runtime.h>

#define HIDDEN 2048
#define NH 16
#define HD 128
#define BATCH 2
#define SEQ 2048

typedef __attribute__((ext_vector_type(8))) short short8;
typedef __attribute__((ext_vector_type(4))) float floatx4;

__device__ inline unsigned short f2bf(float f) {
  union { float f; unsigned int u; } x; x.f = f;
  unsigned int r = x.u + 0x7fffu + ((x.u >> 16) & 1u);
  return (unsigned short)(r >> 16);
}
__device__ inline unsigned int pkbf(float a, float b) {
  return (unsigned int)f2bf(a) | ((unsigned int)f2bf(b) << 16);
}

__device__ inline void async_cp16(const void* g, void* l) {
  __builtin_amdgcn_global_load_lds(
      (const __attribute__((address_space(1))) unsigned int*)g,
      (__attribute__((address_space(3))) unsigned int*)l, 16, 0, 0);
}

// ---------------- f32 -> bf16 convert ----------------
__global__ __launch_bounds__(256) void cvt_kernel(const float* __restrict__ in,
                                                  unsigned short* __restrict__ out,
                                                  int n) {
  int i = (blockIdx.x * 256 + threadIdx.x) * 4;
  if (i + 3 < n) {
    float4 v = *reinterpret_cast<const float4*>(in + i);
    ushort4 o;
    o.x = f2bf(v.x); o.y = f2bf(v.y); o.z = f2bf(v.z); o.w = f2bf(v.w);
    *reinterpret_cast<ushort4*>(out + i) = o;
  }
}

struct QkvPtrs {
  const unsigned short* W[3];
  const float* b[3];
  unsigned short* oq[3];
  float oscale[3];
};

// ---------------- NT GEMM, 256x128 tile, BK=64, 512 thr, counted-vmcnt depth-2 ----
// 3 LDS buffers; per K-step: issue 6 gload_lds for tile t+2, ds_read + 32 MFMA on
// tile t, then s_waitcnt vmcnt(6) (retires tile t+1's loads, keeps t+2's in
// flight) + raw s_barrier. vmcnt never drains to 0 in the main loop (T4).
template<int MODE>
__global__ __launch_bounds__(512, 2) void gemm_nt(const unsigned short* __restrict__ A,
                                                  QkvPtrs P,
                                                  float* __restrict__ outF) {
  __shared__ __align__(16) unsigned short As[3][16384];  // [k8<8][row<256][8] 32KB ea
  __shared__ __align__(16) unsigned short Bs[3][8192];   // [k8<8][row<128][8] 16KB ea
  const int t = threadIdx.x;
  const int lane = t & 63;
  const int w = t >> 6;
  const int wr = w >> 1, wc = w & 1;   // 4 M-waves x 2 N-waves, 64x64 out each
  const int g = lane >> 4;
  const int l15 = lane & 15;

  // XCD-bijective swizzle (nwg % 8 == 0 always here)
  const int nwg = gridDim.x;
  int bid = blockIdx.x;
  int Wi = (bid & 7) * (nwg >> 3) + (bid >> 3);
  const int bx = Wi & 15;            // M-block (M=4096 -> 16 x 256)
  const int byy = Wi >> 4;           // N-block (128 wide), fused over wsel for MODE 0
  const int wsel = (MODE == 0) ? (byy >> 4) : 0;
  const int row0 = bx * 256;
  const int col0 = (MODE == 0) ? ((byy & 15) * 128) : (byy * 128);

  const unsigned short* Bw = P.W[wsel];
  const float* bias = P.b[wsel];

  floatx4 acc[4][4] = {};

#define STAGE(KT, BUF)                                                              \
  {                                                                                 \
    const int kb_ = (KT) * 64;                                                      \
    _Pragma("unroll")                                                               \
    for (int i_ = 0; i_ < 4; ++i_) {                                                \
      int c_ = t + i_ * 512;                                                        \
      async_cp16(A + (size_t)(row0 + (c_ & 255)) * 2048 + kb_ + (c_ >> 8) * 8,      \
                 &As[BUF][c_ * 8]);                                                 \
    }                                                                               \
    _Pragma("unroll")                                                               \
    for (int i_ = 0; i_ < 2; ++i_) {                                                \
      int c_ = t + i_ * 512;                                                        \
      async_cp16(Bw + (size_t)(col0 + (c_ & 127)) * 2048 + kb_ + (c_ >> 7) * 8,     \
                 &Bs[BUF][c_ * 8]);                                                 \
    }                                                                               \
  }

  // prologue: tiles 0 and 1 in flight; wait tile 0 only (vmcnt(6))
  STAGE(0, 0);
  STAGE(1, 1);
  asm volatile("s_waitcnt vmcnt(6)" ::: "memory");
  __builtin_amdgcn_s_barrier();
  __builtin_amdgcn_sched_barrier(0);

  int cb = 0;
  for (int kt = 0; kt < 32; ++kt) {
    const bool pf = (kt + 2 < 32);
    if (pf) {
      const int nb = (cb + 2 >= 3) ? (cb - 1) : (cb + 2);
      STAGE(kt + 2, nb);
    }
    short8 af[2][4], bf[2][4];
#pragma unroll
    for (int ks = 0; ks < 2; ++ks) {
#pragma unroll
      for (int m = 0; m < 4; ++m)
        af[ks][m] = *(const short8*)
            &As[cb][((ks * 4 + g) * 256 + wr * 64 + m * 16 + l15) * 8];
#pragma unroll
      for (int n = 0; n < 4; ++n)
        bf[ks][n] = *(const short8*)
            &Bs[cb][((ks * 4 + g) * 128 + wc * 64 + n * 16 + l15) * 8];
    }
    __builtin_amdgcn_s_setprio(1);
#pragma unroll
    for (int ks = 0; ks < 2; ++ks)
#pragma unroll
      for (int m = 0; m < 4; ++m)
#pragma unroll
        for (int n = 0; n < 4; ++n)
          acc[m][n] = __builtin_amdgcn_mfma_f32_16x16x32_bf16(af[ks][m], bf[ks][n],
                                                              acc[m][n], 0, 0, 0);
    __builtin_amdgcn_s_setprio(0);
    if (pf)
      asm volatile("s_waitcnt vmcnt(6)" ::: "memory");   // tile t+1 resident
    else
      asm volatile("s_waitcnt vmcnt(0)" ::: "memory");   // epilogue drain
    __builtin_amdgcn_s_barrier();
    __builtin_amdgcn_sched_barrier(0);
    cb = (cb + 1 >= 3) ? 0 : (cb + 1);
  }
#undef STAGE

  const float osc = P.oscale[wsel];
#pragma unroll
  for (int m = 0; m < 4; ++m) {
#pragma unroll
    for (int n = 0; n < 4; ++n) {
      int gcol = col0 + wc * 64 + n * 16 + l15;
      float bv = bias[gcol];
#pragma unroll
      for (int r = 0; r < 4; ++r) {
        int grow = row0 + wr * 64 + m * 16 + g * 4 + r;
        float v = acc[m][n][r] + bv;
        if (MODE == 1) {
          outF[(size_t)grow * 2048 + gcol] = v;
        } else {
          int bb = grow >> 11;
          int ss = grow & 2047;
          int hh = gcol >> 7;
          int dd = gcol & 127;
          P.oq[wsel][(((size_t)bb * NH + hh) * SEQ + ss) * HD + dd] = f2bf(v * osc);
        }
      }
    }
  }
}

// ---------------- causal flash attention (round-3 structure, proven 158us) -------
// 4 waves x 32 q = 128 q/block, KVBLK=64, swapped QK^T (mfma(K,Q)), pi-permuted K
// staging so P registers are directly the PV A-fragments. Q pre-scaled in GEMM.
__global__ __launch_bounds__(256) void attn_kernel(const unsigned short* __restrict__ Q,
                                                   const unsigned short* __restrict__ Kg,
                                                   const unsigned short* __restrict__ Vg,
                                                   unsigned short* __restrict__ O) {
  __shared__ __align__(16) unsigned short Ks[16 * 64 * 8];  // [k8][slot][8], 16KB
  __shared__ __align__(16) unsigned short VT[8 * 128 * 8];  // [kvrow][d'][kvlo], 16KB

  const int t = threadIdx.x;
  const int lane = t & 63;
  const int w = t >> 6;
  const int g = lane >> 4;
  const int l15 = lane & 15;

  // work-balance swizzle: pair big causal block with small one
  int gid = blockIdx.x;
  int Wi = (gid < 256) ? gid : 767 - gid;
  const int bx = Wi & 15;
  const int bh = Wi >> 4;
  const int q0 = bx * 128;
  const int bb = bh >> 4;
  const int hh = bh & 15;

  const unsigned short* Qb = Q + (size_t)bh * SEQ * HD;
  const unsigned short* Kb = Kg + (size_t)bh * SEQ * HD;
  const unsigned short* Vb = Vg + (size_t)bh * SEQ * HD;

  const int qw = q0 + w * 32;

  short8 bq[2][4];
#pragma unroll
  for (int qh = 0; qh < 2; ++qh)
#pragma unroll
    for (int kb = 0; kb < 4; ++kb)
      bq[qh][kb] = *(const short8*)(Qb + (size_t)(qw + qh * 16 + l15) * HD + kb * 32 + g * 8);

  floatx4 acc[2][8] = {};
  float mrun[2] = {-1e30f, -1e30f};
  float lrun[2] = {0.f, 0.f};

  const int ntiles = (q0 >> 6) + 2;
  for (int tk = 0; tk < ntiles; ++tk) {
    const int k0 = tk * 64;
    __syncthreads();
    // K stage: LDS slot s holds global kv = 32*(s>>5) + 8*((s>>2)&3) + 4*((s>>4)&1) + (s&3)
#pragma unroll
    for (int cc = 0; cc < 4; ++cc) {
      int c = t + cc * 256;
      int k8 = c >> 6, s = c & 63;
      int kvs = ((s >> 5) << 5) + (((s >> 2) & 3) << 3) + (((s >> 4) & 1) << 2) + (s & 3);
      async_cp16(Kb + (size_t)(k0 + kvs) * HD + k8 * 8, &Ks[c * 8]);
    }
    // V stage transposed: [kv>>3][d ^ ((d>>3 ^ row)&7)][kv&7], u32 kv-pair writes
#pragma unroll
    for (int cc = 0; cc < 2; ++cc) {
      int c = t + cc * 256;
      int kv = (c >> 4) * 2;
      int d0 = (c & 15) * 8;
      int row = kv >> 3;
      short8 va = *(const short8*)(Vb + (size_t)(k0 + kv) * HD + d0);
      short8 vb = *(const short8*)(Vb + (size_t)(k0 + kv + 1) * HD + d0);
#pragma unroll
      for (int j = 0; j < 8; ++j) {
        int d = d0 + j;
        int dp = d ^ (((d >> 3) ^ row) & 7);
        unsigned int u = (unsigned short)va[j] | ((unsigned int)(unsigned short)vb[j] << 16);
        *(unsigned int*)&VT[(row * 128 + dp) * 8 + (kv & 7)] = u;
      }
    }
    __syncthreads();

    // QK^T swapped: C[kv-slot][q]; lane holds q = l15, kv = 32(kvh>>1)+8g+4(kvh&1)+r
    floatx4 sv[4][2];
#pragma unroll
    for (int kvh = 0; kvh < 4; ++kvh) {
      sv[kvh][0] = (floatx4){0.f, 0.f, 0.f, 0.f};
      sv[kvh][1] = (floatx4){0.f, 0.f, 0.f, 0.f};
#pragma unroll
      for (int kb = 0; kb < 4; ++kb) {
        short8 ak = *(const short8*)&Ks[((kb * 4 + g) * 64 + kvh * 16 + l15) * 8];
        sv[kvh][0] = __builtin_amdgcn_mfma_f32_16x16x32_bf16(ak, bq[0][kb], sv[kvh][0], 0, 0, 0);
        sv[kvh][1] = __builtin_amdgcn_mfma_f32_16x16x32_bf16(ak, bq[1][kb], sv[kvh][1], 0, 0, 0);
      }
    }

    // causal mask (Q pre-scaled; no scale mult)
    if (k0 + 63 > qw) {
#pragma unroll
      for (int kvh = 0; kvh < 4; ++kvh)
#pragma unroll
        for (int qh = 0; qh < 2; ++qh)
#pragma unroll
          for (int r = 0; r < 4; ++r) {
            int kvg = k0 + ((kvh >> 1) << 5) + g * 8 + ((kvh & 1) << 2) + r;
            int qg = qw + qh * 16 + l15;
            if (kvg > qg) sv[kvh][qh][r] = -1e30f;
          }
    }

    // online softmax: in-lane 16-value reduce + 2 shfl_xor across groups
#pragma unroll
    for (int qh = 0; qh < 2; ++qh) {
      float mt = sv[0][qh][0];
#pragma unroll
      for (int kvh = 0; kvh < 4; ++kvh)
#pragma unroll
        for (int r = 0; r < 4; ++r)
          mt = fmaxf(mt, sv[kvh][qh][r]);
      mt = fmaxf(mt, __shfl_xor(mt, 16, 64));
      mt = fmaxf(mt, __shfl_xor(mt, 32, 64));
      float mnew = fmaxf(mrun[qh], mt);
      float f = __expf(mrun[qh] - mnew);
      mrun[qh] = mnew;
      float ssum = 0.f;
#pragma unroll
      for (int kvh = 0; kvh < 4; ++kvh)
#pragma unroll
        for (int r = 0; r < 4; ++r) {
          float p = __expf(sv[kvh][qh][r] - mnew);
          sv[kvh][qh][r] = p;
          ssum += p;
        }
      ssum += __shfl_xor(ssum, 16, 64);
      ssum += __shfl_xor(ssum, 32, 64);
      lrun[qh] = lrun[qh] * f + ssum;
      float fr[4];
#pragma unroll
      for (int r = 0; r < 4; ++r)
        fr[r] = __shfl(f, (lane & 48) + 4 * g + r, 64);
#pragma unroll
      for (int db = 0; db < 8; ++db)
#pragma unroll
        for (int r = 0; r < 4; ++r)
          acc[qh][db][r] *= fr[r];
    }

    // PV: P registers are directly the A-fragments (pi-permutation guarantee)
#pragma unroll
    for (int kh = 0; kh < 2; ++kh) {
      union { short8 s8; unsigned int u[4]; } p0, p1;
      p0.u[0] = pkbf(sv[2 * kh][0][0], sv[2 * kh][0][1]);
      p0.u[1] = pkbf(sv[2 * kh][0][2], sv[2 * kh][0][3]);
      p0.u[2] = pkbf(sv[2 * kh + 1][0][0], sv[2 * kh + 1][0][1]);
      p0.u[3] = pkbf(sv[2 * kh + 1][0][2], sv[2 * kh + 1][0][3]);
      p1.u[0] = pkbf(sv[2 * kh][1][0], sv[2 * kh][1][1]);
      p1.u[1] = pkbf(sv[2 * kh][1][2], sv[2 * kh][1][3]);
      p1.u[2] = pkbf(sv[2 * kh + 1][1][0], sv[2 * kh + 1][1][1]);
      p1.u[3] = pkbf(sv[2 * kh + 1][1][2], sv[2 * kh + 1][1][3]);
      int row = kh * 4 + g;
#pragma unroll
      for (int db = 0; db < 8; ++db) {
        int d = db * 16 + l15;
        int dp = d ^ (((d >> 3) ^ row) & 7);
        short8 bv = *(const short8*)&VT[(row * 128 + dp) * 8];
        acc[0][db] = __builtin_amdgcn_mfma_f32_16x16x32_bf16(p0.s8, bv, acc[0][db], 0, 0, 0);
        acc[1][db] = __builtin_amdgcn_mfma_f32_16x16x32_bf16(p1.s8, bv, acc[1][db], 0, 0, 0);
      }
    }
  }

  // epilogue: normalize, write [B][S][HIDDEN]
#pragma unroll
  for (int qh = 0; qh < 2; ++qh) {
    float inv = 1.0f / lrun[qh];
    float ir[4];
#pragma unroll
    for (int r = 0; r < 4; ++r)
      ir[r] = __shfl(inv, (lane & 48) + 4 * g + r, 64);
#pragma unroll
    for (int r = 0; r < 4; ++r) {
      int qg = qw + qh * 16 + 4 * g + r;
      size_t base = ((size_t)bb * SEQ + qg) * HIDDEN + hh * HD;
#pragma unroll
      for (int db = 0; db < 8; ++db)
        O[base + db * 16 + l15] = f2bf(acc[qh][db][r] * ir[r]);
    }
  }
}

extern "C" void kernel_launch(void* const* d_in, const int* in_sizes, int n_in,
                              void* d_out, int out_size, void* d_ws, size_t ws_size,
                              hipStream_t stream) {
  (void)in_sizes; (void)n_in; (void)out_size;
  const float* x  = (const float*)d_in[0];
  const float* Wq = (const float*)d_in[1];
  const float* bq = (const float*)d_in[2];
  const float* Wk = (const float*)d_in[3];
  const float* bk = (const float*)d_in[4];
  const float* Wv = (const float*)d_in[5];
  const float* bv = (const float*)d_in[6];
  const float* Wo = (const float*)d_in[7];
  const float* bo = (const float*)d_in[8];
  float* out = (float*)d_out;

  const float qscale = 0.08838834764831845f;  // 1/sqrt(HD)
  char* ws = (char*)d_ws;
  dim3 blk(256);
  dim3 gblk(512);
  const bool fused = ws_size >= 92274688ull;

  if (fused) {
    unsigned short* xbf = (unsigned short*)ws;                // 16.78MB; reused as attn out
    unsigned short* W0  = (unsigned short*)(ws + 16777216);   // Wq, later Wo
    unsigned short* W1  = (unsigned short*)(ws + 25165824);   // Wk
    unsigned short* W2  = (unsigned short*)(ws + 33554432);   // Wv
    unsigned short* Qbf = (unsigned short*)(ws + 41943040);
    unsigned short* Kbf = (unsigned short*)(ws + 58720256);
    unsigned short* Vbf = (unsigned short*)(ws + 75497472);   // end 92274688

    cvt_kernel<<<8192, blk, 0, stream>>>(x, xbf, BATCH * SEQ * HIDDEN);
    cvt_kernel<<<4096, blk, 0, stream>>>(Wq, W0, HIDDEN * HIDDEN);
    cvt_kernel<<<4096, blk, 0, stream>>>(Wk, W1, HIDDEN * HIDDEN);
    cvt_kernel<<<4096, blk, 0, stream>>>(Wv, W2, HIDDEN * HIDDEN);

    QkvPtrs Pq;
    Pq.W[0] = W0;  Pq.W[1] = W1;  Pq.W[2] = W2;
    Pq.b[0] = bq;  Pq.b[1] = bk;  Pq.b[2] = bv;
    Pq.oq[0] = Qbf; Pq.oq[1] = Kbf; Pq.oq[2] = Vbf;
    Pq.oscale[0] = qscale; Pq.oscale[1] = 1.0f; Pq.oscale[2] = 1.0f;
    gemm_nt<0><<<768, gblk, 0, stream>>>(xbf, Pq, nullptr);   // 16 M x 48 N-blocks

    attn_kernel<<<512, blk, 0, stream>>>(Qbf, Kbf, Vbf, xbf);

    cvt_kernel<<<4096, blk, 0, stream>>>(Wo, W0, HIDDEN * HIDDEN);
    QkvPtrs Po;
    Po.W[0] = W0; Po.W[1] = W0; Po.W[2] = W0;
    Po.b[0] = bo; Po.b[1] = bo; Po.b[2] = bo;
    Po.oq[0] = nullptr; Po.oq[1] = nullptr; Po.oq[2] = nullptr;
    Po.oscale[0] = 1.0f; Po.oscale[1] = 1.0f; Po.oscale[2] = 1.0f;
    gemm_nt<1><<<256, gblk, 0, stream>>>(xbf, Po, out);       // 16 M x 16 N-blocks
  } else {
    unsigned short* xbf = (unsigned short*)ws;
    unsigned short* Wbf = (unsigned short*)(ws + 16777216);
    unsigned short* Qbf = (unsigned short*)(ws + 25165824);
    unsigned short* Kbf = (unsigned short*)(ws + 41943040);
    unsigned short* Vbf = (unsigned short*)(ws + 58720256);

    cvt_kernel<<<8192, blk, 0, stream>>>(x, xbf, BATCH * SEQ * HIDDEN);

    const float* biases[3] = {bq, bk, bv};
    const float* wsrc[3] = {Wq, Wk, Wv};
    unsigned short* outs[3] = {Qbf, Kbf, Vbf};
    float oscales[3] = {qscale, 1.0f, 1.0f};
    for (int i = 0; i < 3; ++i) {
      cvt_kernel<<<4096, blk, 0, stream>>>(wsrc[i], Wbf, HIDDEN * HIDDEN);
      QkvPtrs Pp;
      Pp.W[0] = Wbf; Pp.W[1] = Wbf; Pp.W[2] = Wbf;
      Pp.b[0] = biases[i]; Pp.b[1] = biases[i]; Pp.b[2] = biases[i];
      Pp.oq[0] = outs[i]; Pp.oq[1] = outs[i]; Pp.oq[2] = outs[i];
      Pp.oscale[0] = oscales[i]; Pp.oscale[1] = oscales[i]; Pp.oscale[2] = oscales[i];
      gemm_nt<0><<<256, gblk, 0, stream>>>(xbf, Pp, nullptr);
    }

    attn_kernel<<<512, blk, 0, stream>>>(Qbf, Kbf, Vbf, xbf);

    cvt_kernel<<<4096, blk, 0, stream>>>(Wo, Wbf, HIDDEN * HIDDEN);
    QkvPtrs Po;
    Po.W[0] = Wbf; Po.W[1] = Wbf; Po.W[2] = Wbf;
    Po.b[0] = bo; Po.b[1] = bo; Po.b[2] = bo;
    Po.oq[0] = nullptr; Po.oq[1] = nullptr; Po.oq[2] = nullptr;
    Po.oscale[0] = 1.0f; Po.oscale[1] = 1.0f; Po.oscale[2] = 1.0f;
    gemm_nt<1><<<256, gblk, 0, stream>>>(xbf, Po, out);
  }
}

// Round 7
// 603.825 us; speedup vs baseline: 1.0346x; 1.0346x over previous
//
#include <hip/hip_runtime.h>

#define HIDDEN 2048
#define NH 16
#define HD 128
#define BATCH 2
#define SEQ 2048

typedef __attribute__((ext_vector_type(8))) short short8;
typedef __attribute__((ext_vector_type(4))) float floatx4;

__device__ inline unsigned short f2bf(float f) {
  union { float f; unsigned int u; } x; x.f = f;
  unsigned int r = x.u + 0x7fffu + ((x.u >> 16) & 1u);
  return (unsigned short)(r >> 16);
}
__device__ inline unsigned int pkbf(float a, float b) {
  return (unsigned int)f2bf(a) | ((unsigned int)f2bf(b) << 16);
}

__device__ inline void async_cp16(const void* g, void* l) {
  __builtin_amdgcn_global_load_lds(
      (const __attribute__((address_space(1))) unsigned int*)g,
      (__attribute__((address_space(3))) unsigned int*)l, 16, 0, 0);
}

// ---------------- f32 -> bf16 convert ----------------
__global__ __launch_bounds__(256) void cvt_kernel(const float* __restrict__ in,
                                                  unsigned short* __restrict__ out,
                                                  int n) {
  int i = (blockIdx.x * 256 + threadIdx.x) * 4;
  if (i + 3 < n) {
    float4 v = *reinterpret_cast<const float4*>(in + i);
    ushort4 o;
    o.x = f2bf(v.x); o.y = f2bf(v.y); o.z = f2bf(v.z); o.w = f2bf(v.w);
    *reinterpret_cast<ushort4*>(out + i) = o;
  }
}

struct QkvPtrs {
  const unsigned short* W[3];
  const float* b[3];
  unsigned short* oq[3];
  float oscale[3];
};

// ---------------- NT GEMM, 128x128 tile, BK=32, SINGLE-buffer, max-TLP ----------
// m97-exact structure: 16 KB LDS + ~56 VGPR -> up to 8 blocks/CU co-resident;
// cross-block wave overlap (m114) fills the per-step staging drain. QKV grid
// 1536 = 6 blocks/CU all resident.
template<int MODE>
__global__ __launch_bounds__(256) void gemm_nt(const unsigned short* __restrict__ A,
                                               QkvPtrs P,
                                               float* __restrict__ outF) {
  __shared__ __align__(16) unsigned short As[4096];  // [k8<4][row<128][8], 8KB
  __shared__ __align__(16) unsigned short Bs[4096];  // 8KB
  const int t = threadIdx.x;
  const int lane = t & 63;
  const int w = t >> 6;
  const int wr = w >> 1, wc = w & 1;
  const int g = lane >> 4;
  const int l15 = lane & 15;

  // XCD-bijective swizzle (nwg % 8 == 0 always here)
  const int nwg = gridDim.x;
  int bid = blockIdx.x;
  int Wi = (bid & 7) * (nwg >> 3) + (bid >> 3);
  const int bx = Wi & 31;            // M-block (M=4096 -> 32 x 128)
  const int byy = Wi >> 5;           // N-block (128 wide), fused over wsel for MODE 0
  const int wsel = (MODE == 0) ? (byy >> 4) : 0;
  const int row0 = bx * 128;
  const int col0 = (MODE == 0) ? ((byy & 15) * 128) : (byy * 128);

  const unsigned short* Bw = P.W[wsel];
  const float* bias = P.b[wsel];

  floatx4 acc[4][4] = {};

#define STAGE(KT)                                                               \
  {                                                                             \
    const int kb_ = (KT) * 32;                                                  \
    _Pragma("unroll")                                                           \
    for (int cc_ = 0; cc_ < 2; ++cc_) {                                         \
      int c_ = t + cc_ * 256;                                                   \
      int k8_ = c_ >> 7, r_ = c_ & 127;                                         \
      async_cp16(A + (size_t)(row0 + r_) * 2048 + kb_ + k8_ * 8, &As[c_ * 8]);  \
      async_cp16(Bw + (size_t)(col0 + r_) * 2048 + kb_ + k8_ * 8, &Bs[c_ * 8]); \
    }                                                                           \
  }

  STAGE(0);
  for (int kt = 0; kt < 64; ++kt) {
    __syncthreads();  // drains stage(kt); all waves aligned
    short8 af[4], bf[4];
#pragma unroll
    for (int m = 0; m < 4; ++m)
      af[m] = *(const short8*)&As[(g * 128 + wr * 64 + m * 16 + l15) * 8];
#pragma unroll
    for (int n = 0; n < 4; ++n)
      bf[n] = *(const short8*)&Bs[(g * 128 + wc * 64 + n * 16 + l15) * 8];
#pragma unroll
    for (int m = 0; m < 4; ++m)
#pragma unroll
      for (int n = 0; n < 4; ++n)
        acc[m][n] = __builtin_amdgcn_mfma_f32_16x16x32_bf16(af[m], bf[n], acc[m][n], 0, 0, 0);
    if (kt < 63) {
      __syncthreads();  // all waves done reading before restage
      STAGE(kt + 1);
    }
  }
#undef STAGE

  const float osc = P.oscale[wsel];
#pragma unroll
  for (int m = 0; m < 4; ++m) {
#pragma unroll
    for (int n = 0; n < 4; ++n) {
      int gcol = col0 + wc * 64 + n * 16 + l15;
      float bv = bias[gcol];
#pragma unroll
      for (int r = 0; r < 4; ++r) {
        int grow = row0 + wr * 64 + m * 16 + g * 4 + r;
        float v = acc[m][n][r] + bv;
        if (MODE == 1) {
          outF[(size_t)grow * 2048 + gcol] = v;
        } else {
          int bb = grow >> 11;
          int ss = grow & 2047;
          int hh = gcol >> 7;
          int dd = gcol & 127;
          P.oq[wsel][(((size_t)bb * NH + hh) * SEQ + ss) * HD + dd] = f2bf(v * osc);
        }
      }
    }
  }
}

// ---------------- causal flash attention (UNCHANGED: round-3 structure) ----------
// 4 waves x 32 q = 128 q/block, KVBLK=64, swapped QK^T (mfma(K,Q)), pi-permuted K
// staging so P registers are directly the PV A-fragments. Q pre-scaled in GEMM.
__global__ __launch_bounds__(256) void attn_kernel(const unsigned short* __restrict__ Q,
                                                   const unsigned short* __restrict__ Kg,
                                                   const unsigned short* __restrict__ Vg,
                                                   unsigned short* __restrict__ O) {
  __shared__ __align__(16) unsigned short Ks[16 * 64 * 8];  // [k8][slot][8], 16KB
  __shared__ __align__(16) unsigned short VT[8 * 128 * 8];  // [kvrow][d'][kvlo], 16KB

  const int t = threadIdx.x;
  const int lane = t & 63;
  const int w = t >> 6;
  const int g = lane >> 4;
  const int l15 = lane & 15;

  // reversal pairing: co-resident blocks (round-robin by gid) get complementary work
  int gid = blockIdx.x;
  int Wi = (gid < 256) ? gid : 767 - gid;
  const int bx = Wi & 15;
  const int bh = Wi >> 4;
  const int q0 = bx * 128;
  const int bb = bh >> 4;
  const int hh = bh & 15;

  const unsigned short* Qb = Q + (size_t)bh * SEQ * HD;
  const unsigned short* Kb = Kg + (size_t)bh * SEQ * HD;
  const unsigned short* Vb = Vg + (size_t)bh * SEQ * HD;

  const int qw = q0 + w * 32;

  short8 bq[2][4];
#pragma unroll
  for (int qh = 0; qh < 2; ++qh)
#pragma unroll
    for (int kb = 0; kb < 4; ++kb)
      bq[qh][kb] = *(const short8*)(Qb + (size_t)(qw + qh * 16 + l15) * HD + kb * 32 + g * 8);

  floatx4 acc[2][8] = {};
  float mrun[2] = {-1e30f, -1e30f};
  float lrun[2] = {0.f, 0.f};

  const int ntiles = (q0 >> 6) + 2;
  for (int tk = 0; tk < ntiles; ++tk) {
    const int k0 = tk * 64;
    __syncthreads();
    // K stage: LDS slot s holds global kv = 32*(s>>5) + 8*((s>>2)&3) + 4*((s>>4)&1) + (s&3)
#pragma unroll
    for (int cc = 0; cc < 4; ++cc) {
      int c = t + cc * 256;
      int k8 = c >> 6, s = c & 63;
      int kvs = ((s >> 5) << 5) + (((s >> 2) & 3) << 3) + (((s >> 4) & 1) << 2) + (s & 3);
      async_cp16(Kb + (size_t)(k0 + kvs) * HD + k8 * 8, &Ks[c * 8]);
    }
    // V stage transposed: [kv>>3][d ^ ((d>>3 ^ row)&7)][kv&7], u32 kv-pair writes
#pragma unroll
    for (int cc = 0; cc < 2; ++cc) {
      int c = t + cc * 256;
      int kv = (c >> 4) * 2;
      int d0 = (c & 15) * 8;
      int row = kv >> 3;
      short8 va = *(const short8*)(Vb + (size_t)(k0 + kv) * HD + d0);
      short8 vb = *(const short8*)(Vb + (size_t)(k0 + kv + 1) * HD + d0);
#pragma unroll
      for (int j = 0; j < 8; ++j) {
        int d = d0 + j;
        int dp = d ^ (((d >> 3) ^ row) & 7);
        unsigned int u = (unsigned short)va[j] | ((unsigned int)(unsigned short)vb[j] << 16);
        *(unsigned int*)&VT[(row * 128 + dp) * 8 + (kv & 7)] = u;
      }
    }
    __syncthreads();

    // QK^T swapped: C[kv-slot][q]; lane holds q = l15, kv = 32(kvh>>1)+8g+4(kvh&1)+r
    floatx4 sv[4][2];
#pragma unroll
    for (int kvh = 0; kvh < 4; ++kvh) {
      sv[kvh][0] = (floatx4){0.f, 0.f, 0.f, 0.f};
      sv[kvh][1] = (floatx4){0.f, 0.f, 0.f, 0.f};
#pragma unroll
      for (int kb = 0; kb < 4; ++kb) {
        short8 ak = *(const short8*)&Ks[((kb * 4 + g) * 64 + kvh * 16 + l15) * 8];
        sv[kvh][0] = __builtin_amdgcn_mfma_f32_16x16x32_bf16(ak, bq[0][kb], sv[kvh][0], 0, 0, 0);
        sv[kvh][1] = __builtin_amdgcn_mfma_f32_16x16x32_bf16(ak, bq[1][kb], sv[kvh][1], 0, 0, 0);
      }
    }

    // causal mask (Q pre-scaled; no scale mult)
    if (k0 + 63 > qw) {
#pragma unroll
      for (int kvh = 0; kvh < 4; ++kvh)
#pragma unroll
        for (int qh = 0; qh < 2; ++qh)
#pragma unroll
          for (int r = 0; r < 4; ++r) {
            int kvg = k0 + ((kvh >> 1) << 5) + g * 8 + ((kvh & 1) << 2) + r;
            int qg = qw + qh * 16 + l15;
            if (kvg > qg) sv[kvh][qh][r] = -1e30f;
          }
    }

    // online softmax: in-lane 16-value reduce + 2 shfl_xor across groups
#pragma unroll
    for (int qh = 0; qh < 2; ++qh) {
      float mt = sv[0][qh][0];
#pragma unroll
      for (int kvh = 0; kvh < 4; ++kvh)
#pragma unroll
        for (int r = 0; r < 4; ++r)
          mt = fmaxf(mt, sv[kvh][qh][r]);
      mt = fmaxf(mt, __shfl_xor(mt, 16, 64));
      mt = fmaxf(mt, __shfl_xor(mt, 32, 64));
      float mnew = fmaxf(mrun[qh], mt);
      float f = __expf(mrun[qh] - mnew);
      mrun[qh] = mnew;
      float ssum = 0.f;
#pragma unroll
      for (int kvh = 0; kvh < 4; ++kvh)
#pragma unroll
        for (int r = 0; r < 4; ++r) {
          float p = __expf(sv[kvh][qh][r] - mnew);
          sv[kvh][qh][r] = p;
          ssum += p;
        }
      ssum += __shfl_xor(ssum, 16, 64);
      ssum += __shfl_xor(ssum, 32, 64);
      lrun[qh] = lrun[qh] * f + ssum;
      float fr[4];
#pragma unroll
      for (int r = 0; r < 4; ++r)
        fr[r] = __shfl(f, (lane & 48) + 4 * g + r, 64);
#pragma unroll
      for (int db = 0; db < 8; ++db)
#pragma unroll
        for (int r = 0; r < 4; ++r)
          acc[qh][db][r] *= fr[r];
    }

    // PV: P registers are directly the A-fragments (pi-permutation guarantee)
#pragma unroll
    for (int kh = 0; kh < 2; ++kh) {
      union { short8 s8; unsigned int u[4]; } p0, p1;
      p0.u[0] = pkbf(sv[2 * kh][0][0], sv[2 * kh][0][1]);
      p0.u[1] = pkbf(sv[2 * kh][0][2], sv[2 * kh][0][3]);
      p0.u[2] = pkbf(sv[2 * kh + 1][0][0], sv[2 * kh + 1][0][1]);
      p0.u[3] = pkbf(sv[2 * kh + 1][0][2], sv[2 * kh + 1][0][3]);
      p1.u[0] = pkbf(sv[2 * kh][1][0], sv[2 * kh][1][1]);
      p1.u[1] = pkbf(sv[2 * kh][1][2], sv[2 * kh][1][3]);
      p1.u[2] = pkbf(sv[2 * kh + 1][1][0], sv[2 * kh + 1][1][1]);
      p1.u[3] = pkbf(sv[2 * kh + 1][1][2], sv[2 * kh + 1][1][3]);
      int row = kh * 4 + g;
#pragma unroll
      for (int db = 0; db < 8; ++db) {
        int d = db * 16 + l15;
        int dp = d ^ (((d >> 3) ^ row) & 7);
        short8 bv = *(const short8*)&VT[(row * 128 + dp) * 8];
        acc[0][db] = __builtin_amdgcn_mfma_f32_16x16x32_bf16(p0.s8, bv, acc[0][db], 0, 0, 0);
        acc[1][db] = __builtin_amdgcn_mfma_f32_16x16x32_bf16(p1.s8, bv, acc[1][db], 0, 0, 0);
      }
    }
  }

  // epilogue: normalize, write [B][S][HIDDEN]
#pragma unroll
  for (int qh = 0; qh < 2; ++qh) {
    float inv = 1.0f / lrun[qh];
    float ir[4];
#pragma unroll
    for (int r = 0; r < 4; ++r)
      ir[r] = __shfl(inv, (lane & 48) + 4 * g + r, 64);
#pragma unroll
    for (int r = 0; r < 4; ++r) {
      int qg = qw + qh * 16 + 4 * g + r;
      size_t base = ((size_t)bb * SEQ + qg) * HIDDEN + hh * HD;
#pragma unroll
      for (int db = 0; db < 8; ++db)
        O[base + db * 16 + l15] = f2bf(acc[qh][db][r] * ir[r]);
    }
  }
}

extern "C" void kernel_launch(void* const* d_in, const int* in_sizes, int n_in,
                              void* d_out, int out_size, void* d_ws, size_t ws_size,
                              hipStream_t stream) {
  (void)in_sizes; (void)n_in; (void)out_size;
  const float* x  = (const float*)d_in[0];
  const float* Wq = (const float*)d_in[1];
  const float* bq = (const float*)d_in[2];
  const float* Wk = (const float*)d_in[3];
  const float* bk = (const float*)d_in[4];
  const float* Wv = (const float*)d_in[5];
  const float* bv = (const float*)d_in[6];
  const float* Wo = (const float*)d_in[7];
  const float* bo = (const float*)d_in[8];
  float* out = (float*)d_out;

  const float qscale = 0.08838834764831845f;  // 1/sqrt(HD)
  char* ws = (char*)d_ws;
  dim3 blk(256);
  const bool fused = ws_size >= 92274688ull;

  if (fused) {
    unsigned short* xbf = (unsigned short*)ws;                // 16.78MB; reused as attn out
    unsigned short* W0  = (unsigned short*)(ws + 16777216);   // Wq, later Wo
    unsigned short* W1  = (unsigned short*)(ws + 25165824);   // Wk
    unsigned short* W2  = (unsigned short*)(ws + 33554432);   // Wv
    unsigned short* Qbf = (unsigned short*)(ws + 41943040);
    unsigned short* Kbf = (unsigned short*)(ws + 58720256);
    unsigned short* Vbf = (unsigned short*)(ws + 75497472);   // end 92274688

    cvt_kernel<<<8192, blk, 0, stream>>>(x, xbf, BATCH * SEQ * HIDDEN);
    cvt_kernel<<<4096, blk, 0, stream>>>(Wq, W0, HIDDEN * HIDDEN);
    cvt_kernel<<<4096, blk, 0, stream>>>(Wk, W1, HIDDEN * HIDDEN);
    cvt_kernel<<<4096, blk, 0, stream>>>(Wv, W2, HIDDEN * HIDDEN);

    QkvPtrs Pq;
    Pq.W[0] = W0;  Pq.W[1] = W1;  Pq.W[2] = W2;
    Pq.b[0] = bq;  Pq.b[1] = bk;  Pq.b[2] = bv;
    Pq.oq[0] = Qbf; Pq.oq[1] = Kbf; Pq.oq[2] = Vbf;
    Pq.oscale[0] = qscale; Pq.oscale[1] = 1.0f; Pq.oscale[2] = 1.0f;
    gemm_nt<0><<<1536, blk, 0, stream>>>(xbf, Pq, nullptr);   // 32 M x 48 N-blocks

    attn_kernel<<<512, blk, 0, stream>>>(Qbf, Kbf, Vbf, xbf);

    cvt_kernel<<<4096, blk, 0, stream>>>(Wo, W0, HIDDEN * HIDDEN);
    QkvPtrs Po;
    Po.W[0] = W0; Po.W[1] = W0; Po.W[2] = W0;
    Po.b[0] = bo; Po.b[1] = bo; Po.b[2] = bo;
    Po.oq[0] = nullptr; Po.oq[1] = nullptr; Po.oq[2] = nullptr;
    Po.oscale[0] = 1.0f; Po.oscale[1] = 1.0f; Po.oscale[2] = 1.0f;
    gemm_nt<1><<<512, blk, 0, stream>>>(xbf, Po, out);        // 32 M x 16 N-blocks
  } else {
    unsigned short* xbf = (unsigned short*)ws;
    unsigned short* Wbf = (unsigned short*)(ws + 16777216);
    unsigned short* Qbf = (unsigned short*)(ws + 25165824);
    unsigned short* Kbf = (unsigned short*)(ws + 41943040);
    unsigned short* Vbf = (unsigned short*)(ws + 58720256);

    cvt_kernel<<<8192, blk, 0, stream>>>(x, xbf, BATCH * SEQ * HIDDEN);

    const float* biases[3] = {bq, bk, bv};
    const float* wsrc[3] = {Wq, Wk, Wv};
    unsigned short* outs[3] = {Qbf, Kbf, Vbf};
    float oscales[3] = {qscale, 1.0f, 1.0f};
    for (int i = 0; i < 3; ++i) {
      cvt_kernel<<<4096, blk, 0, stream>>>(wsrc[i], Wbf, HIDDEN * HIDDEN);
      QkvPtrs Pp;
      Pp.W[0] = Wbf; Pp.W[1] = Wbf; Pp.W[2] = Wbf;
      Pp.b[0] = biases[i]; Pp.b[1] = biases[i]; Pp.b[2] = biases[i];
      Pp.oq[0] = outs[i]; Pp.oq[1] = outs[i]; Pp.oq[2] = outs[i];
      Pp.oscale[0] = oscales[i]; Pp.oscale[1] = oscales[i]; Pp.oscale[2] = oscales[i];
      gemm_nt<0><<<512, blk, 0, stream>>>(xbf, Pp, nullptr);
    }

    attn_kernel<<<512, blk, 0, stream>>>(Qbf, Kbf, Vbf, xbf);

    cvt_kernel<<<4096, blk, 0, stream>>>(Wo, Wbf, HIDDEN * HIDDEN);
    QkvPtrs Po;
    Po.W[0] = Wbf; Po.W[1] = Wbf; Po.W[2] = Wbf;
    Po.b[0] = bo; Po.b[1] = bo; Po.b[2] = bo;
    Po.oq[0] = nullptr; Po.oq[1] = nullptr; Po.oq[2] = nullptr;
    Po.oscale[0] = 1.0f; Po.oscale[1] = 1.0f; Po.oscale[2] = 1.0f;
    gemm_nt<1><<<512, blk, 0, stream>>>(xbf, Po, out);
  }
}

// Round 8
// 537.366 us; speedup vs baseline: 1.1625x; 1.1237x over previous
//
#include <hip/hip_runtime.h>

#define HIDDEN 2048
#define NH 16
#define HD 128
#define BATCH 2
#define SEQ 2048

typedef __attribute__((ext_vector_type(8))) short short8;
typedef __attribute__((ext_vector_type(4))) float floatx4;

__device__ inline unsigned short f2bf(float f) {
  union { float f; unsigned int u; } x; x.f = f;
  unsigned int r = x.u + 0x7fffu + ((x.u >> 16) & 1u);
  return (unsigned short)(r >> 16);
}
__device__ inline unsigned int pkbf(float a, float b) {
  return (unsigned int)f2bf(a) | ((unsigned int)f2bf(b) << 16);
}

__device__ inline void async_cp16(const void* g, void* l) {
  __builtin_amdgcn_global_load_lds(
      (const __attribute__((address_space(1))) unsigned int*)g,
      (__attribute__((address_space(3))) unsigned int*)l, 16, 0, 0);
}

// ---------------- f32 -> bf16 convert ----------------
__global__ __launch_bounds__(256) void cvt_kernel(const float* __restrict__ in,
                                                  unsigned short* __restrict__ out,
                                                  int n) {
  int i = (blockIdx.x * 256 + threadIdx.x) * 4;
  if (i + 3 < n) {
    float4 v = *reinterpret_cast<const float4*>(in + i);
    ushort4 o;
    o.x = f2bf(v.x); o.y = f2bf(v.y); o.z = f2bf(v.z); o.w = f2bf(v.w);
    *reinterpret_cast<ushort4*>(out + i) = o;
  }
}

struct QkvPtrs {
  const unsigned short* W[3];
  const float* b[3];
  unsigned short* oq[3];
  float oscale[3];
};

// ---------------- NT GEMM, 256x128 tile, BK=64, 512 thr, 4-phase pipelined ------
// 3 LDS buffers (race-free depth-2: stage T+2 while computing T, T+1 resident).
// Per K-step, 4 phases of {ds_read subtile + 2 gload_lds -> barrier -> lgkmcnt(0)
// -> 8 MFMA} (fine interleave per m196); vmcnt(6) once per step retires T+1.
template<int MODE>
__global__ __launch_bounds__(512) void gemm_nt(const unsigned short* __restrict__ A,
                                               QkvPtrs P,
                                               float* __restrict__ outF) {
  __shared__ __align__(16) unsigned short As[3][16384];  // [k8<8][row<256][8] 32KB ea
  __shared__ __align__(16) unsigned short Bs[3][8192];   // [k8<8][row<128][8] 16KB ea
  const int t = threadIdx.x;
  const int lane = t & 63;
  const int w = t >> 6;
  const int wr = w >> 1, wc = w & 1;   // 4 M-waves x 2 N-waves -> 64x64 per wave
  const int g = lane >> 4;
  const int l15 = lane & 15;

  // XCD-bijective swizzle (nwg % 8 == 0 always here)
  const int nwg = gridDim.x;
  int bid = blockIdx.x;
  int Wi = (bid & 7) * (nwg >> 3) + (bid >> 3);
  const int bx = Wi & 15;            // M-block (M=4096 -> 16 x 256)
  const int byy = Wi >> 4;           // N-block (128 wide); fused over wsel for MODE 0
  const int wsel = (MODE == 0) ? (byy >> 4) : 0;
  const int row0 = bx * 256;
  const int col0 = (MODE == 0) ? ((byy & 15) * 128) : (byy * 128);

  const unsigned short* Bw = P.W[wsel];
  const float* bias = P.b[wsel];

  // loop-invariant per-thread source bases (A: 4 chunks, B: 2 chunks)
  const unsigned short* srcA[4];
  const unsigned short* srcB[2];
  int dstA[4], dstB[2];
#pragma unroll
  for (int i = 0; i < 4; ++i) {
    int c = t + i * 512;                       // 0..2047
    srcA[i] = A + (size_t)(row0 + (c & 255)) * 2048 + (c >> 8) * 8;
    dstA[i] = c * 8;
  }
#pragma unroll
  for (int i = 0; i < 2; ++i) {
    int c = t + i * 512;                       // 0..1023
    srcB[i] = Bw + (size_t)(col0 + (c & 127)) * 2048 + (c >> 7) * 8;
    dstB[i] = c * 8;
  }

  floatx4 acc[4][4] = {};

  // prologue: tiles 0,1 staged; tile 0 resident (vmcnt(6) keeps tile1's 6 in flight)
#pragma unroll
  for (int i = 0; i < 4; ++i) async_cp16(srcA[i], &As[0][dstA[i]]);
#pragma unroll
  for (int i = 0; i < 2; ++i) async_cp16(srcB[i], &Bs[0][dstB[i]]);
#pragma unroll
  for (int i = 0; i < 4; ++i) async_cp16(srcA[i] + 64, &As[1][dstA[i]]);
#pragma unroll
  for (int i = 0; i < 2; ++i) async_cp16(srcB[i] + 64, &Bs[1][dstB[i]]);
  asm volatile("s_waitcnt vmcnt(6)" ::: "memory");
  __builtin_amdgcn_s_barrier();
  __builtin_amdgcn_sched_barrier(0);

  int cb = 0;
  for (int kt = 0; kt < 32; ++kt) {
    const bool pf = (kt + 2 < 32);
    const int nb = (cb + 2 >= 3) ? (cb - 1) : (cb + 2);   // stage buffer for T+2
    const int kbn = (kt + 2) * 64;
    const unsigned short* a0 = &As[cb][0];
    const unsigned short* b0 = &Bs[cb][0];

    short8 bfr[2][4], af[2];

    // ---- phase 0: B[ks0] + A[m01,ks0]; stage A chunks 0,1 ----
#pragma unroll
    for (int n = 0; n < 4; ++n)
      bfr[0][n] = *(const short8*)&b0[((0 * 4 + g) * 128 + wc * 64 + n * 16 + l15) * 8];
    af[0] = *(const short8*)&a0[((0 * 4 + g) * 256 + wr * 64 + 0 * 16 + l15) * 8];
    af[1] = *(const short8*)&a0[((0 * 4 + g) * 256 + wr * 64 + 1 * 16 + l15) * 8];
    if (pf) { async_cp16(srcA[0] + kbn, &As[nb][dstA[0]]);
              async_cp16(srcA[1] + kbn, &As[nb][dstA[1]]); }
    __builtin_amdgcn_s_barrier();
    asm volatile("s_waitcnt lgkmcnt(0)" ::: "memory");
    __builtin_amdgcn_sched_barrier(0);
    __builtin_amdgcn_s_setprio(1);
#pragma unroll
    for (int m = 0; m < 2; ++m)
#pragma unroll
      for (int n = 0; n < 4; ++n)
        acc[m][n] = __builtin_amdgcn_mfma_f32_16x16x32_bf16(af[m], bfr[0][n], acc[m][n], 0, 0, 0);
    __builtin_amdgcn_s_setprio(0);
    __builtin_amdgcn_s_barrier();
    __builtin_amdgcn_sched_barrier(0);

    // ---- phase 1: B[ks1] + A[m01,ks1]; stage A chunks 2,3 ----
#pragma unroll
    for (int n = 0; n < 4; ++n)
      bfr[1][n] = *(const short8*)&b0[((1 * 4 + g) * 128 + wc * 64 + n * 16 + l15) * 8];
    af[0] = *(const short8*)&a0[((1 * 4 + g) * 256 + wr * 64 + 0 * 16 + l15) * 8];
    af[1] = *(const short8*)&a0[((1 * 4 + g) * 256 + wr * 64 + 1 * 16 + l15) * 8];
    if (pf) { async_cp16(srcA[2] + kbn, &As[nb][dstA[2]]);
              async_cp16(srcA[3] + kbn, &As[nb][dstA[3]]); }
    __builtin_amdgcn_s_barrier();
    asm volatile("s_waitcnt lgkmcnt(0)" ::: "memory");
    __builtin_amdgcn_sched_barrier(0);
    __builtin_amdgcn_s_setprio(1);
#pragma unroll
    for (int m = 0; m < 2; ++m)
#pragma unroll
      for (int n = 0; n < 4; ++n)
        acc[m][n] = __builtin_amdgcn_mfma_f32_16x16x32_bf16(af[m], bfr[1][n], acc[m][n], 0, 0, 0);
    __builtin_amdgcn_s_setprio(0);
    __builtin_amdgcn_s_barrier();
    __builtin_amdgcn_sched_barrier(0);

    // ---- phase 2: A[m23,ks0] (B[ks0] live); stage B chunks 0,1 ----
    af[0] = *(const short8*)&a0[((0 * 4 + g) * 256 + wr * 64 + 2 * 16 + l15) * 8];
    af[1] = *(const short8*)&a0[((0 * 4 + g) * 256 + wr * 64 + 3 * 16 + l15) * 8];
    if (pf) { async_cp16(srcB[0] + kbn, &Bs[nb][dstB[0]]);
              async_cp16(srcB[1] + kbn, &Bs[nb][dstB[1]]); }
    __builtin_amdgcn_s_barrier();
    asm volatile("s_waitcnt lgkmcnt(0)" ::: "memory");
    __builtin_amdgcn_sched_barrier(0);
    __builtin_amdgcn_s_setprio(1);
#pragma unroll
    for (int m = 0; m < 2; ++m)
#pragma unroll
      for (int n = 0; n < 4; ++n)
        acc[m + 2][n] = __builtin_amdgcn_mfma_f32_16x16x32_bf16(af[m], bfr[0][n], acc[m + 2][n], 0, 0, 0);
    __builtin_amdgcn_s_setprio(0);
    __builtin_amdgcn_s_barrier();
    __builtin_amdgcn_sched_barrier(0);

    // ---- phase 3: A[m23,ks1] (B[ks1] live); no stage; step vmcnt ----
    af[0] = *(const short8*)&a0[((1 * 4 + g) * 256 + wr * 64 + 2 * 16 + l15) * 8];
    af[1] = *(const short8*)&a0[((1 * 4 + g) * 256 + wr * 64 + 3 * 16 + l15) * 8];
    __builtin_amdgcn_s_barrier();
    asm volatile("s_waitcnt lgkmcnt(0)" ::: "memory");
    __builtin_amdgcn_sched_barrier(0);
    __builtin_amdgcn_s_setprio(1);
#pragma unroll
    for (int m = 0; m < 2; ++m)
#pragma unroll
      for (int n = 0; n < 4; ++n)
        acc[m + 2][n] = __builtin_amdgcn_mfma_f32_16x16x32_bf16(af[m], bfr[1][n], acc[m + 2][n], 0, 0, 0);
    __builtin_amdgcn_s_setprio(0);
    if (pf)
      asm volatile("s_waitcnt vmcnt(6)" ::: "memory");   // retires tile T+1's loads
    else
      asm volatile("s_waitcnt vmcnt(0)" ::: "memory");   // epilogue drain
    __builtin_amdgcn_s_barrier();
    __builtin_amdgcn_sched_barrier(0);

    cb = (cb + 1 >= 3) ? 0 : (cb + 1);
  }

  const float osc = P.oscale[wsel];
#pragma unroll
  for (int m = 0; m < 4; ++m) {
#pragma unroll
    for (int n = 0; n < 4; ++n) {
      int gcol = col0 + wc * 64 + n * 16 + l15;
      float bv = bias[gcol];
#pragma unroll
      for (int r = 0; r < 4; ++r) {
        int grow = row0 + wr * 64 + m * 16 + g * 4 + r;
        float v = acc[m][n][r] + bv;
        if (MODE == 1) {
          outF[(size_t)grow * 2048 + gcol] = v;
        } else {
          int bb = grow >> 11;
          int ss = grow & 2047;
          int hh = gcol >> 7;
          int dd = gcol & 127;
          P.oq[wsel][(((size_t)bb * NH + hh) * SEQ + ss) * HD + dd] = f2bf(v * osc);
        }
      }
    }
  }
}

// ---------------- causal flash attention (UNCHANGED: round-3 structure) ----------
__global__ __launch_bounds__(256) void attn_kernel(const unsigned short* __restrict__ Q,
                                                   const unsigned short* __restrict__ Kg,
                                                   const unsigned short* __restrict__ Vg,
                                                   unsigned short* __restrict__ O) {
  __shared__ __align__(16) unsigned short Ks[16 * 64 * 8];  // [k8][slot][8], 16KB
  __shared__ __align__(16) unsigned short VT[8 * 128 * 8];  // [kvrow][d'][kvlo], 16KB

  const int t = threadIdx.x;
  const int lane = t & 63;
  const int w = t >> 6;
  const int g = lane >> 4;
  const int l15 = lane & 15;

  int gid = blockIdx.x;
  int Wi = (gid < 256) ? gid : 767 - gid;
  const int bx = Wi & 15;
  const int bh = Wi >> 4;
  const int q0 = bx * 128;
  const int bb = bh >> 4;
  const int hh = bh & 15;

  const unsigned short* Qb = Q + (size_t)bh * SEQ * HD;
  const unsigned short* Kb = Kg + (size_t)bh * SEQ * HD;
  const unsigned short* Vb = Vg + (size_t)bh * SEQ * HD;

  const int qw = q0 + w * 32;

  short8 bq[2][4];
#pragma unroll
  for (int qh = 0; qh < 2; ++qh)
#pragma unroll
    for (int kb = 0; kb < 4; ++kb)
      bq[qh][kb] = *(const short8*)(Qb + (size_t)(qw + qh * 16 + l15) * HD + kb * 32 + g * 8);

  floatx4 acc[2][8] = {};
  float mrun[2] = {-1e30f, -1e30f};
  float lrun[2] = {0.f, 0.f};

  const int ntiles = (q0 >> 6) + 2;
  for (int tk = 0; tk < ntiles; ++tk) {
    const int k0 = tk * 64;
    __syncthreads();
#pragma unroll
    for (int cc = 0; cc < 4; ++cc) {
      int c = t + cc * 256;
      int k8 = c >> 6, s = c & 63;
      int kvs = ((s >> 5) << 5) + (((s >> 2) & 3) << 3) + (((s >> 4) & 1) << 2) + (s & 3);
      async_cp16(Kb + (size_t)(k0 + kvs) * HD + k8 * 8, &Ks[c * 8]);
    }
#pragma unroll
    for (int cc = 0; cc < 2; ++cc) {
      int c = t + cc * 256;
      int kv = (c >> 4) * 2;
      int d0 = (c & 15) * 8;
      int row = kv >> 3;
      short8 va = *(const short8*)(Vb + (size_t)(k0 + kv) * HD + d0);
      short8 vb = *(const short8*)(Vb + (size_t)(k0 + kv + 1) * HD + d0);
#pragma unroll
      for (int j = 0; j < 8; ++j) {
        int d = d0 + j;
        int dp = d ^ (((d >> 3) ^ row) & 7);
        unsigned int u = (unsigned short)va[j] | ((unsigned int)(unsigned short)vb[j] << 16);
        *(unsigned int*)&VT[(row * 128 + dp) * 8 + (kv & 7)] = u;
      }
    }
    __syncthreads();

    floatx4 sv[4][2];
#pragma unroll
    for (int kvh = 0; kvh < 4; ++kvh) {
      sv[kvh][0] = (floatx4){0.f, 0.f, 0.f, 0.f};
      sv[kvh][1] = (floatx4){0.f, 0.f, 0.f, 0.f};
#pragma unroll
      for (int kb = 0; kb < 4; ++kb) {
        short8 ak = *(const short8*)&Ks[((kb * 4 + g) * 64 + kvh * 16 + l15) * 8];
        sv[kvh][0] = __builtin_amdgcn_mfma_f32_16x16x32_bf16(ak, bq[0][kb], sv[kvh][0], 0, 0, 0);
        sv[kvh][1] = __builtin_amdgcn_mfma_f32_16x16x32_bf16(ak, bq[1][kb], sv[kvh][1], 0, 0, 0);
      }
    }

    if (k0 + 63 > qw) {
#pragma unroll
      for (int kvh = 0; kvh < 4; ++kvh)
#pragma unroll
        for (int qh = 0; qh < 2; ++qh)
#pragma unroll
          for (int r = 0; r < 4; ++r) {
            int kvg = k0 + ((kvh >> 1) << 5) + g * 8 + ((kvh & 1) << 2) + r;
            int qg = qw + qh * 16 + l15;
            if (kvg > qg) sv[kvh][qh][r] = -1e30f;
          }
    }

#pragma unroll
    for (int qh = 0; qh < 2; ++qh) {
      float mt = sv[0][qh][0];
#pragma unroll
      for (int kvh = 0; kvh < 4; ++kvh)
#pragma unroll
        for (int r = 0; r < 4; ++r)
          mt = fmaxf(mt, sv[kvh][qh][r]);
      mt = fmaxf(mt, __shfl_xor(mt, 16, 64));
      mt = fmaxf(mt, __shfl_xor(mt, 32, 64));
      float mnew = fmaxf(mrun[qh], mt);
      float f = __expf(mrun[qh] - mnew);
      mrun[qh] = mnew;
      float ssum = 0.f;
#pragma unroll
      for (int kvh = 0; kvh < 4; ++kvh)
#pragma unroll
        for (int r = 0; r < 4; ++r) {
          float p = __expf(sv[kvh][qh][r] - mnew);
          sv[kvh][qh][r] = p;
          ssum += p;
        }
      ssum += __shfl_xor(ssum, 16, 64);
      ssum += __shfl_xor(ssum, 32, 64);
      lrun[qh] = lrun[qh] * f + ssum;
      float fr[4];
#pragma unroll
      for (int r = 0; r < 4; ++r)
        fr[r] = __shfl(f, (lane & 48) + 4 * g + r, 64);
#pragma unroll
      for (int db = 0; db < 8; ++db)
#pragma unroll
        for (int r = 0; r < 4; ++r)
          acc[qh][db][r] *= fr[r];
    }

#pragma unroll
    for (int kh = 0; kh < 2; ++kh) {
      union { short8 s8; unsigned int u[4]; } p0, p1;
      p0.u[0] = pkbf(sv[2 * kh][0][0], sv[2 * kh][0][1]);
      p0.u[1] = pkbf(sv[2 * kh][0][2], sv[2 * kh][0][3]);
      p0.u[2] = pkbf(sv[2 * kh + 1][0][0], sv[2 * kh + 1][0][1]);
      p0.u[3] = pkbf(sv[2 * kh + 1][0][2], sv[2 * kh + 1][0][3]);
      p1.u[0] = pkbf(sv[2 * kh][1][0], sv[2 * kh][1][1]);
      p1.u[1] = pkbf(sv[2 * kh][1][2], sv[2 * kh][1][3]);
      p1.u[2] = pkbf(sv[2 * kh + 1][1][0], sv[2 * kh + 1][1][1]);
      p1.u[3] = pkbf(sv[2 * kh + 1][1][2], sv[2 * kh + 1][1][3]);
      int row = kh * 4 + g;
#pragma unroll
      for (int db = 0; db < 8; ++db) {
        int d = db * 16 + l15;
        int dp = d ^ (((d >> 3) ^ row) & 7);
        short8 bv = *(const short8*)&VT[(row * 128 + dp) * 8];
        acc[0][db] = __builtin_amdgcn_mfma_f32_16x16x32_bf16(p0.s8, bv, acc[0][db], 0, 0, 0);
        acc[1][db] = __builtin_amdgcn_mfma_f32_16x16x32_bf16(p1.s8, bv, acc[1][db], 0, 0, 0);
      }
    }
  }

#pragma unroll
  for (int qh = 0; qh < 2; ++qh) {
    float inv = 1.0f / lrun[qh];
    float ir[4];
#pragma unroll
    for (int r = 0; r < 4; ++r)
      ir[r] = __shfl(inv, (lane & 48) + 4 * g + r, 64);
#pragma unroll
    for (int r = 0; r < 4; ++r) {
      int qg = qw + qh * 16 + 4 * g + r;
      size_t base = ((size_t)bb * SEQ + qg) * HIDDEN + hh * HD;
#pragma unroll
      for (int db = 0; db < 8; ++db)
        O[base + db * 16 + l15] = f2bf(acc[qh][db][r] * ir[r]);
    }
  }
}

extern "C" void kernel_launch(void* const* d_in, const int* in_sizes, int n_in,
                              void* d_out, int out_size, void* d_ws, size_t ws_size,
                              hipStream_t stream) {
  (void)in_sizes; (void)n_in; (void)out_size;
  const float* x  = (const float*)d_in[0];
  const float* Wq = (const float*)d_in[1];
  const float* bq = (const float*)d_in[2];
  const float* Wk = (const float*)d_in[3];
  const float* bk = (const float*)d_in[4];
  const float* Wv = (const float*)d_in[5];
  const float* bv = (const float*)d_in[6];
  const float* Wo = (const float*)d_in[7];
  const float* bo = (const float*)d_in[8];
  float* out = (float*)d_out;

  const float qscale = 0.08838834764831845f;  // 1/sqrt(HD)
  char* ws = (char*)d_ws;
  dim3 blk(256);
  dim3 gblk(512);
  const bool fused = ws_size >= 92274688ull;

  if (fused) {
    unsigned short* xbf = (unsigned short*)ws;                // 16.78MB; reused as attn out
    unsigned short* W0  = (unsigned short*)(ws + 16777216);   // Wq, later Wo
    unsigned short* W1  = (unsigned short*)(ws + 25165824);   // Wk
    unsigned short* W2  = (unsigned short*)(ws + 33554432);   // Wv
    unsigned short* Qbf = (unsigned short*)(ws + 41943040);
    unsigned short* Kbf = (unsigned short*)(ws + 58720256);
    unsigned short* Vbf = (unsigned short*)(ws + 75497472);   // end 92274688

    cvt_kernel<<<8192, blk, 0, stream>>>(x, xbf, BATCH * SEQ * HIDDEN);
    cvt_kernel<<<4096, blk, 0, stream>>>(Wq, W0, HIDDEN * HIDDEN);
    cvt_kernel<<<4096, blk, 0, stream>>>(Wk, W1, HIDDEN * HIDDEN);
    cvt_kernel<<<4096, blk, 0, stream>>>(Wv, W2, HIDDEN * HIDDEN);

    QkvPtrs Pq;
    Pq.W[0] = W0;  Pq.W[1] = W1;  Pq.W[2] = W2;
    Pq.b[0] = bq;  Pq.b[1] = bk;  Pq.b[2] = bv;
    Pq.oq[0] = Qbf; Pq.oq[1] = Kbf; Pq.oq[2] = Vbf;
    Pq.oscale[0] = qscale; Pq.oscale[1] = 1.0f; Pq.oscale[2] = 1.0f;
    gemm_nt<0><<<768, gblk, 0, stream>>>(xbf, Pq, nullptr);   // 16 M x 48 N-blocks

    attn_kernel<<<512, blk, 0, stream>>>(Qbf, Kbf, Vbf, xbf);

    cvt_kernel<<<4096, blk, 0, stream>>>(Wo, W0, HIDDEN * HIDDEN);
    QkvPtrs Po;
    Po.W[0] = W0; Po.W[1] = W0; Po.W[2] = W0;
    Po.b[0] = bo; Po.b[1] = bo; Po.b[2] = bo;
    Po.oq[0] = nullptr; Po.oq[1] = nullptr; Po.oq[2] = nullptr;
    Po.oscale[0] = 1.0f; Po.oscale[1] = 1.0f; Po.oscale[2] = 1.0f;
    gemm_nt<1><<<256, gblk, 0, stream>>>(xbf, Po, out);       // 16 M x 16 N-blocks
  } else {
    unsigned short* xbf = (unsigned short*)ws;
    unsigned short* Wbf = (unsigned short*)(ws + 16777216);
    unsigned short* Qbf = (unsigned short*)(ws + 25165824);
    unsigned short* Kbf = (unsigned short*)(ws + 41943040);
    unsigned short* Vbf = (unsigned short*)(ws + 58720256);

    cvt_kernel<<<8192, blk, 0, stream>>>(x, xbf, BATCH * SEQ * HIDDEN);

    const float* biases[3] = {bq, bk, bv};
    const float* wsrc[3] = {Wq, Wk, Wv};
    unsigned short* outs[3] = {Qbf, Kbf, Vbf};
    float oscales[3] = {qscale, 1.0f, 1.0f};
    for (int i = 0; i < 3; ++i) {
      cvt_kernel<<<4096, blk, 0, stream>>>(wsrc[i], Wbf, HIDDEN * HIDDEN);
      QkvPtrs Pp;
      Pp.W[0] = Wbf; Pp.W[1] = Wbf; Pp.W[2] = Wbf;
      Pp.b[0] = biases[i]; Pp.b[1] = biases[i]; Pp.b[2] = biases[i];
      Pp.oq[0] = outs[i]; Pp.oq[1] = outs[i]; Pp.oq[2] = outs[i];
      Pp.oscale[0] = oscales[i]; Pp.oscale[1] = oscales[i]; Pp.oscale[2] = oscales[i];
      gemm_nt<0><<<256, gblk, 0, stream>>>(xbf, Pp, nullptr);
    }

    attn_kernel<<<512, blk, 0, stream>>>(Qbf, Kbf, Vbf, xbf);

    cvt_kernel<<<4096, blk, 0, stream>>>(Wo, Wbf, HIDDEN * HIDDEN);
    QkvPtrs Po;
    Po.W[0] = Wbf; Po.W[1] = Wbf; Po.W[2] = Wbf;
    Po.b[0] = bo; Po.b[1] = bo; Po.b[2] = bo;
    Po.oq[0] = nullptr; Po.oq[1] = nullptr; Po.oq[2] = nullptr;
    Po.oscale[0] = 1.0f; Po.oscale[1] = 1.0f; Po.oscale[2] = 1.0f;
    gemm_nt<1><<<256, gblk, 0, stream>>>(xbf, Po, out);
  }
}